// Round 7
// baseline (302.245 us; speedup 1.0000x reference)
//
#include <hip/hip_runtime.h>

typedef short s16x8 __attribute__((ext_vector_type(8)));   // 8 bf16 (4 VGPR) MFMA frag
typedef float f32x4 __attribute__((ext_vector_type(4)));   // MFMA C/D frag

#define NTOK 65536
#define CCH 64
#define KCB 1024
#define HWSZ 4096
#define CHW 262144            // C*H*W
#define NXQ 4194304           // B*C*H*W
#define NMEAN 4194304.0       // N*C
#define PLANE_BYTES 131072    // 1024 codes * 64 ch * 2B

static __device__ __forceinline__ unsigned short f2bf(float f) {
    unsigned int u = __float_as_uint(f);
    return (unsigned short)((u + 0x7FFFu + ((u >> 16) & 1u)) >> 16);  // RNE
}
static __device__ __forceinline__ float bf2f(unsigned short b) {
    return __uint_as_float(((unsigned int)b) << 16);
}

// ---------------------------------------------------------------------------
// Kernel 1 (8192 thr over 128 blocks -> 128 CUs): pack -2*E into 3 bf16
// split planes in MFMA-B frag order; e2[k] = ||E[k]||^2; zero loss.
// Plane entry gid = nt*128 + ks*64 + l holds code col=(l&15) of N-tile nt,
// channels c = ks*32 + (l>>4)*8 + j  (same (g,j)->c map as the A frags, so
// the in-fragment k-permutation cancels in the MFMA dot).
// ---------------------------------------------------------------------------
__global__ void vq_prep(const float* __restrict__ E, float* __restrict__ e2,
                        s16x8* __restrict__ Bh, s16x8* __restrict__ Bm,
                        s16x8* __restrict__ Bl, double* __restrict__ loss_acc) {
    int gid = blockIdx.x * blockDim.x + threadIdx.x;   // 0..8191
    if (gid == 0) *loss_acc = 0.0;
    {
        int nt = gid >> 7, rem = gid & 127;
        int ks = rem >> 6, l = rem & 63;
        int code = nt * 16 + (l & 15);
        int cb   = ks * 32 + ((l >> 4) << 3);
        const float* ep = E + code * CCH + cb;
        s16x8 vh, vm, vl;
#pragma unroll
        for (int j = 0; j < 8; ++j) {
            float v = -2.f * ep[j];                    // exact scaling
            unsigned short h  = f2bf(v);  float r1 = v  - bf2f(h);
            unsigned short md = f2bf(r1); float r2 = r1 - bf2f(md);
            unsigned short lo = f2bf(r2);
            vh[j] = (short)h; vm[j] = (short)md; vl[j] = (short)lo;
        }
        Bh[gid] = vh; Bm[gid] = vm; Bl[gid] = vl;
    }
    if (gid < KCB) {
        const float4* e4 = reinterpret_cast<const float4*>(E + gid * CCH);
        float s = 0.f;
#pragma unroll
        for (int i = 0; i < 16; ++i) {
            float4 v = e4[i];
            s = fmaf(v.x, v.x, s); s = fmaf(v.y, v.y, s);
            s = fmaf(v.z, v.z, s); s = fmaf(v.w, v.w, s);
        }
        e2[gid] = s;
    }
}

// ---------------------------------------------------------------------------
// Kernel 2: MFMA VQ. 1024 WGs x 256 thr (4 waves). WG owns 64 tokens.
//   4 independent blocks/CU (VGPR<=128, LDS 27.6KB) -> 16 waves/CU, and
//   blocks are barrier-decoupled so B-load stalls hide across blocks
//   (round-6 fix: was 8-wave/512-thr blocks at ~1 block/CU, Occ 18.5%).
//   Wave w scans codes [w*256,(w+1)*256) in 8 chunks of 32: acc seeded
//   with e2[k]; 6 split-MFMAs (hh,hm,mh,mm,hl,lh) give s = e2 - 2 x.e at
//   ~f32 precision (HW-validated r6: absmax 2^-9, no index flips).
//   Per-lane argmin (strict <, k asc), 16-lane shfl reduce (tie -> lower
//   k), 4-wave LDS combine (asc k).
// ---------------------------------------------------------------------------
__global__ __launch_bounds__(256, 4) void vq_main(
    const float* __restrict__ x, const float* __restrict__ E,
    const s16x8* __restrict__ Bh, const s16x8* __restrict__ Bm,
    const s16x8* __restrict__ Bl, const float* __restrict__ e2,
    float* __restrict__ out, double* __restrict__ loss_acc)
{
    __shared__ __align__(16) short XH[64 * 64];
    __shared__ __align__(16) short XM[64 * 64];
    __shared__ __align__(16) short XL[64 * 64];
    __shared__ float XSQ[4][64];
    __shared__ float SB[4][64];
    __shared__ int   SI[4][64];

    const int t    = threadIdx.x;
    const int lane = t & 63;
    const int w    = t >> 6;                   // 0..3
    const int n0   = blockIdx.x * 64;
    const int b    = n0 >> 12;                 // constant per block (64|4096)
    const int hw0  = n0 & 4095;

    // ---- stage x: thread handles channels cb*16..cb*16+15 of token tok ----
    {
        const int tok = t & 63;
        const int cb  = t >> 6;                // 0..3
        const float* xp = x + b * CHW + hw0 + tok;
        float xs = 0.f;
        const int swz = (tok & 7) << 4;
#pragma unroll
        for (int h = 0; h < 2; ++h) {
            s16x8 ph, pm, pl;
#pragma unroll
            for (int j = 0; j < 8; ++j) {
                float v = xp[(cb * 16 + h * 8 + j) * HWSZ];   // coalesced per j
                xs = fmaf(v, v, xs);
                unsigned short hb = f2bf(v);  float r1 = v  - bf2f(hb);
                unsigned short md = f2bf(r1); float r2 = r1 - bf2f(md);
                unsigned short lo = f2bf(r2);
                ph[j] = (short)hb; pm[j] = (short)md; pl[j] = (short)lo;
            }
            const int wofs = tok * 128 + (((cb * 32) + h * 16) ^ swz);
            *reinterpret_cast<s16x8*>((char*)XH + wofs) = ph;
            *reinterpret_cast<s16x8*>((char*)XM + wofs) = pm;
            *reinterpret_cast<s16x8*>((char*)XL + wofs) = pl;
        }
        XSQ[cb][tok] = xs;
    }
    __syncthreads();

    const int g   = lane >> 4;
    const int c15 = lane & 15;

    // ---- hoist A-frags: [m][ks], 24 x s16x8 ----
    s16x8 ah[4][2], am[4][2], al[4][2];
#pragma unroll
    for (int m = 0; m < 4; ++m) {
        const int row = m * 16 + c15;
        const int rb  = row * 128;
        const int swz = (row & 7) << 4;
#pragma unroll
        for (int ks = 0; ks < 2; ++ks) {
            int off = rb + ((ks * 64 + g * 16) ^ swz);
            ah[m][ks] = *reinterpret_cast<const s16x8*>((const char*)XH + off);
            am[m][ks] = *reinterpret_cast<const s16x8*>((const char*)XM + off);
            al[m][ks] = *reinterpret_cast<const s16x8*>((const char*)XL + off);
        }
    }

    float e2w[16];
#pragma unroll
    for (int i = 0; i < 16; ++i) e2w[i] = e2[w * 256 + i * 16 + c15];

    float best[4][4];
    int   bidx[4][4];
#pragma unroll
    for (int m = 0; m < 4; ++m)
#pragma unroll
        for (int r = 0; r < 4; ++r) { best[m][r] = 3.4e38f; bidx[m][r] = 0; }

#pragma unroll 1
    for (int ch = 0; ch < 8; ++ch) {
        s16x8 bh[2][2], bm[2][2], bl[2][2];          // [nt][ks]
#pragma unroll
        for (int nt = 0; nt < 2; ++nt)
#pragma unroll
            for (int ks = 0; ks < 2; ++ks) {
                int idx = ((w * 16 + ch * 2 + nt) * 2 + ks) * 64 + lane;
                bh[nt][ks] = Bh[idx];
                bm[nt][ks] = Bm[idx];
                bl[nt][ks] = Bl[idx];
            }

        f32x4 acc[4][2];
#pragma unroll
        for (int m = 0; m < 4; ++m)
#pragma unroll
            for (int nt = 0; nt < 2; ++nt) {
                float s0 = e2w[ch * 2 + nt];          // seed: ||e||^2
                acc[m][nt] = (f32x4){s0, s0, s0, s0};
            }

#pragma unroll
        for (int m = 0; m < 4; ++m)
#pragma unroll
            for (int nt = 0; nt < 2; ++nt)
#pragma unroll
                for (int ks = 0; ks < 2; ++ks) {
                    acc[m][nt] = __builtin_amdgcn_mfma_f32_16x16x32_bf16(ah[m][ks], bh[nt][ks], acc[m][nt], 0, 0, 0);
                    acc[m][nt] = __builtin_amdgcn_mfma_f32_16x16x32_bf16(ah[m][ks], bm[nt][ks], acc[m][nt], 0, 0, 0);
                    acc[m][nt] = __builtin_amdgcn_mfma_f32_16x16x32_bf16(am[m][ks], bh[nt][ks], acc[m][nt], 0, 0, 0);
                    acc[m][nt] = __builtin_amdgcn_mfma_f32_16x16x32_bf16(am[m][ks], bm[nt][ks], acc[m][nt], 0, 0, 0);
                    acc[m][nt] = __builtin_amdgcn_mfma_f32_16x16x32_bf16(ah[m][ks], bl[nt][ks], acc[m][nt], 0, 0, 0);
                    acc[m][nt] = __builtin_amdgcn_mfma_f32_16x16x32_bf16(al[m][ks], bh[nt][ks], acc[m][nt], 0, 0, 0);
                }

        // argmin update: nt ascending => k ascending; strict < keeps first
#pragma unroll
        for (int nt = 0; nt < 2; ++nt) {
            const int k = w * 256 + ch * 32 + nt * 16 + c15;
#pragma unroll
            for (int m = 0; m < 4; ++m)
#pragma unroll
                for (int r = 0; r < 4; ++r) {
                    float s = acc[m][nt][r];
                    if (s < best[m][r]) { best[m][r] = s; bidx[m][r] = k; }
                }
        }
    }

    // ---- cross-lane reduce over the 16 cols (same token rows) ----
#pragma unroll
    for (int m = 0; m < 4; ++m)
#pragma unroll
        for (int r = 0; r < 4; ++r) {
            float v = best[m][r]; int k = bidx[m][r];
#pragma unroll
            for (int off = 1; off < 16; off <<= 1) {
                float ov = __shfl_xor(v, off, 64);
                int   ok = __shfl_xor(k, off, 64);
                if (ov < v || (ov == v && ok < k)) { v = ov; k = ok; }
            }
            if (c15 == 0) {
                int tk = m * 16 + g * 4 + r;       // C/D row (m89-verified)
                SB[w][tk] = v; SI[w][tk] = k;
            }
        }
    __syncthreads();

    // ---- wave 0: combine 4 waves (asc wave = asc k), outputs ----
    if (w == 0) {
        float bv = SB[0][lane]; int bi = SI[0][lane];
#pragma unroll
        for (int ww = 1; ww < 4; ++ww) {
            float v = SB[ww][lane];
            if (v < bv) { bv = v; bi = SI[ww][lane]; }
        }
        out[NXQ + 2 + n0 + lane] = (float)bi;

        float xsq = 0.f;
#pragma unroll
        for (int c = 0; c < 4; ++c) xsq += XSQ[c][lane];
        float lsum = bv + xsq;                     // ||x-q||^2
#pragma unroll
        for (int off = 32; off > 0; off >>= 1)
            lsum += __shfl_xor(lsum, off, 64);
        if (lane == 0) atomicAdd(loss_acc, (double)lsum);

        // x_q = E[bi] (exact f32 copy), coalesced per-channel scatter
        const float4* eq = reinterpret_cast<const float4*>(E + bi * CCH);
        float* oq = out + b * CHW + hw0 + lane;
#pragma unroll 1
        for (int gq = 0; gq < 4; ++gq) {
            float4 q0 = eq[4 * gq + 0];
            float4 q1 = eq[4 * gq + 1];
            float4 q2 = eq[4 * gq + 2];
            float4 q3 = eq[4 * gq + 3];
            float* o = oq + (16 * gq) * HWSZ;
            o[0 * HWSZ] = q0.x; o[1 * HWSZ]  = q0.y; o[2 * HWSZ]  = q0.z; o[3 * HWSZ]  = q0.w;
            o[4 * HWSZ] = q1.x; o[5 * HWSZ]  = q1.y; o[6 * HWSZ]  = q1.z; o[7 * HWSZ]  = q1.w;
            o[8 * HWSZ] = q2.x; o[9 * HWSZ]  = q2.y; o[10 * HWSZ] = q2.z; o[11 * HWSZ] = q2.w;
            o[12 * HWSZ] = q3.x; o[13 * HWSZ] = q3.y; o[14 * HWSZ] = q3.z; o[15 * HWSZ] = q3.w;
        }
    }
}

// ---------------------------------------------------------------------------
// Kernel 3: finalize both loss scalars (forward values identical).
// ---------------------------------------------------------------------------
__global__ void vq_final(const double* __restrict__ loss_acc,
                         float* __restrict__ out) {
    if (threadIdx.x == 0) {
        float m = (float)(*loss_acc / NMEAN);
        out[NXQ]     = m;
        out[NXQ + 1] = m;
    }
}

// ---------------------------------------------------------------------------
extern "C" void kernel_launch(void* const* d_in, const int* in_sizes, int n_in,
                              void* d_out, int out_size, void* d_ws, size_t ws_size,
                              hipStream_t stream) {
    const float* x = (const float*)d_in[0];          // [16,64,64,64] f32
    const float* E = (const float*)d_in[1];          // [1024,64] f32
    float* out = (float*)d_out;                      // [x_q | cb | cm | idx]
    double* loss_acc = (double*)d_ws;                // 8 B
    float*  e2 = (float*)((char*)d_ws + 64);         // 4 KB
    s16x8*  Bh = (s16x8*)((char*)d_ws + 8192);
    s16x8*  Bm = (s16x8*)((char*)d_ws + 8192 + PLANE_BYTES);
    s16x8*  Bl = (s16x8*)((char*)d_ws + 8192 + 2 * PLANE_BYTES);

    vq_prep <<<128,  64,  0, stream>>>(E, e2, Bh, Bm, Bl, loss_acc);
    vq_main <<<1024, 256, 0, stream>>>(x, E, Bh, Bm, Bl, e2, out, loss_acc);
    vq_final<<<1,    64,  0, stream>>>(loss_acc, out);
}

// Round 9
// 128.320 us; speedup vs baseline: 2.3554x; 2.3554x over previous
//
#include <hip/hip_runtime.h>

typedef short s16x8 __attribute__((ext_vector_type(8)));   // 8 bf16 (4 VGPR) MFMA frag
typedef float f32x4 __attribute__((ext_vector_type(4)));   // MFMA C/D frag

#define CCH 64
#define KCB 1024
#define HWSZ 4096
#define CHW 262144            // C*H*W
#define NXQ 4194304           // B*C*H*W
#define NMEAN 4194304.0       // N*C
#define PLANE_BYTES 131072    // 1024 codes * 64 ch * 2B

static __device__ __forceinline__ unsigned short f2bf(float f) {
    unsigned int u = __float_as_uint(f);
    return (unsigned short)((u + 0x7FFFu + ((u >> 16) & 1u)) >> 16);  // RNE
}
static __device__ __forceinline__ float bf2f(unsigned short b) {
    return __uint_as_float(((unsigned int)b) << 16);
}

// ---------------------------------------------------------------------------
// Kernel 1 (8192 thr): pack -2*E into 3 bf16 split planes in MFMA-B frag
// order; e2[k] = ||E[k]||^2; zero loss accumulator. Plane entry
// gid = nt*128 + ks*64 + l holds code col=(l&15) of N-tile nt, channels
// c = ks*32 + (l>>4)*8 + j (same (g,j)->c map as A frags: permutation
// cancels in the MFMA dot — HW-validated r6).
// ---------------------------------------------------------------------------
__global__ void vq_prep(const float* __restrict__ E, float* __restrict__ e2,
                        s16x8* __restrict__ Bh, s16x8* __restrict__ Bm,
                        s16x8* __restrict__ Bl, double* __restrict__ loss_acc) {
    int gid = blockIdx.x * blockDim.x + threadIdx.x;   // 0..8191
    if (gid == 0) *loss_acc = 0.0;
    {
        int nt = gid >> 7, rem = gid & 127;
        int ks = rem >> 6, l = rem & 63;
        int code = nt * 16 + (l & 15);
        int cb   = ks * 32 + ((l >> 4) << 3);
        const float* ep = E + code * CCH + cb;
        s16x8 vh, vm, vl;
#pragma unroll
        for (int j = 0; j < 8; ++j) {
            float v = -2.f * ep[j];                    // exact scaling
            unsigned short h  = f2bf(v);  float r1 = v  - bf2f(h);
            unsigned short md = f2bf(r1); float r2 = r1 - bf2f(md);
            unsigned short lo = f2bf(r2);
            vh[j] = (short)h; vm[j] = (short)md; vl[j] = (short)lo;
        }
        Bh[gid] = vh; Bm[gid] = vm; Bl[gid] = vl;
    }
    if (gid < KCB) {
        const float4* e4 = reinterpret_cast<const float4*>(E + gid * CCH);
        float s = 0.f;
#pragma unroll
        for (int i = 0; i < 16; ++i) {
            float4 v = e4[i];
            s = fmaf(v.x, v.x, s); s = fmaf(v.y, v.y, s);
            s = fmaf(v.z, v.z, s); s = fmaf(v.w, v.w, s);
        }
        e2[gid] = s;
    }
}

// ---------------------------------------------------------------------------
// Kernel 2: MFMA VQ. 512 WGs x 256 thr (4 waves); 2 independent blocks/CU.
//   WG owns 128 tokens; wave w owns M-tiles {2w,2w+1} (32 tokens) with
//   A-frags IN REGISTERS (12 s16x8, direct global load). All waves sweep
//   all 1024 codes in 32 chunks of 32; B chunk (768 s16x8 = 12KB) staged
//   in LDS double-buffer (T14: global->reg early, ds_write late). MT=2:
//   each B ds_read_b128 feeds 2 MFMAs -> per-CU LDS 49k cyc < MFMA 59.6k
//   (r8 static fix: MT=1 was 98k, LDS-bound). Live regs ~120 under a
//   (256,2) bound: no spill by construction (r7 lesson). Distances
//   bit-identical to r6-validated run (same split, same MFMA order).
// ---------------------------------------------------------------------------
__global__ __launch_bounds__(256, 2) void vq_main(
    const float* __restrict__ x, const float* __restrict__ E,
    const s16x8* __restrict__ Bh, const s16x8* __restrict__ Bm,
    const s16x8* __restrict__ Bl, const float* __restrict__ e2,
    float* __restrict__ out, double* __restrict__ loss_acc)
{
    __shared__ s16x8 BB[2][768];          // 24 KB: [buf][plane*256 + (nt*2+ks)*64 + lane]
    __shared__ float BVL[128];
    __shared__ int   BIL[128];
    __shared__ float XSL[128];

    const int t    = threadIdx.x;         // 0..255
    const int lane = t & 63;
    const int w    = t >> 6;              // wave 0..3
    const int g    = lane >> 4;           // k-group
    const int c15  = lane & 15;
    const int n0   = blockIdx.x * 128;
    const int b    = n0 >> 12;            // 128 | 4096: same b for whole block
    const int hw0  = n0 & 4095;

    // ---- A-frags direct from global: [mt][ks]; token = n0+w*32+mt*16+c15 ----
    s16x8 ah[2][2], am[2][2], al[2][2];
#pragma unroll
    for (int mt = 0; mt < 2; ++mt) {
        const float* xp = x + b * CHW + hw0 + w * 32 + mt * 16 + c15;
        float xs = 0.f;
#pragma unroll
        for (int ks = 0; ks < 2; ++ks)
#pragma unroll
            for (int j = 0; j < 8; ++j) {
                float v = xp[(ks * 32 + g * 8 + j) * HWSZ];
                xs = fmaf(v, v, xs);
                unsigned short h  = f2bf(v);  float r1 = v  - bf2f(h);
                unsigned short md = f2bf(r1); float r2 = r1 - bf2f(md);
                unsigned short lo = f2bf(r2);
                ah[mt][ks][j] = (short)h; am[mt][ks][j] = (short)md; al[mt][ks][j] = (short)lo;
            }
        // per-token ||x||^2: sum the 4 k-groups (lanes ^16, ^32)
        xs += __shfl_xor(xs, 16, 64);
        xs += __shfl_xor(xs, 32, 64);
        if (lane < 16) XSL[w * 32 + mt * 16 + lane] = xs;
    }

    // ---- stage chunk 0: [0,256)=Bh, [256,512)=Bm, [512,768)=Bl ----
    BB[0][t] = Bh[t]; BB[0][256 + t] = Bm[t]; BB[0][512 + t] = Bl[t];
    __syncthreads();

    float best[2][4]; int bidx[2][4];
#pragma unroll
    for (int mt = 0; mt < 2; ++mt)
#pragma unroll
        for (int r = 0; r < 4; ++r) { best[mt][r] = 3.4e38f; bidx[mt][r] = 0; }

    int buf = 0;
#pragma unroll 1
    for (int ch = 0; ch < 32; ++ch) {
        // T14: issue next chunk's global loads NOW; ds_write after compute
        s16x8 sH, sM, sL;
        const int nb = (ch + 1) * 256 + t;
        if (ch < 31) { sH = Bh[nb]; sM = Bm[nb]; sL = Bl[nb]; }

#pragma unroll
        for (int nt = 0; nt < 2; ++nt) {
            const float s0 = e2[ch * 32 + nt * 16 + c15];    // seed ||e||^2
            s16x8 bh[2], bm[2], bl[2];
#pragma unroll
            for (int ks = 0; ks < 2; ++ks) {
                const int q = (nt * 2 + ks) * 64 + lane;
                bh[ks] = BB[buf][q];
                bm[ks] = BB[buf][256 + q];
                bl[ks] = BB[buf][512 + q];
            }
#pragma unroll
            for (int mt = 0; mt < 2; ++mt) {
                f32x4 acc = (f32x4){s0, s0, s0, s0};
#pragma unroll
                for (int ks = 0; ks < 2; ++ks) {       // r6 order: bit-identical s
                    acc = __builtin_amdgcn_mfma_f32_16x16x32_bf16(ah[mt][ks], bh[ks], acc, 0, 0, 0);
                    acc = __builtin_amdgcn_mfma_f32_16x16x32_bf16(ah[mt][ks], bm[ks], acc, 0, 0, 0);
                    acc = __builtin_amdgcn_mfma_f32_16x16x32_bf16(am[mt][ks], bh[ks], acc, 0, 0, 0);
                    acc = __builtin_amdgcn_mfma_f32_16x16x32_bf16(am[mt][ks], bm[ks], acc, 0, 0, 0);
                    acc = __builtin_amdgcn_mfma_f32_16x16x32_bf16(ah[mt][ks], bl[ks], acc, 0, 0, 0);
                    acc = __builtin_amdgcn_mfma_f32_16x16x32_bf16(al[mt][ks], bh[ks], acc, 0, 0, 0);
                }
                const int k = ch * 32 + nt * 16 + c15;  // ch,nt asc => k asc
#pragma unroll
                for (int r = 0; r < 4; ++r) {
                    float s = acc[r];
                    if (s < best[mt][r]) { best[mt][r] = s; bidx[mt][r] = k; }  // strict <
                }
            }
        }

        if (ch < 31) {
            BB[buf ^ 1][t] = sH; BB[buf ^ 1][256 + t] = sM; BB[buf ^ 1][512 + t] = sL;
        }
        __syncthreads();
        buf ^= 1;
    }

    // ---- argmin reduce over 16 code-cols (tie -> lower k) ----
#pragma unroll
    for (int mt = 0; mt < 2; ++mt)
#pragma unroll
        for (int r = 0; r < 4; ++r) {
            float v = best[mt][r]; int k = bidx[mt][r];
#pragma unroll
            for (int off = 1; off < 16; off <<= 1) {
                float ov = __shfl_xor(v, off, 64);
                int   ok = __shfl_xor(k, off, 64);
                if (ov < v || (ov == v && ok < k)) { v = ov; k = ok; }
            }
            if (c15 == 0) {                  // token row = g*4 + r (m89 map)
                BVL[w * 32 + mt * 16 + g * 4 + r] = v;
                BIL[w * 32 + mt * 16 + g * 4 + r] = k;
            }
        }
    __syncthreads();

    // ---- epilogue: wave w -> token group (w&1)*64, channel half w>>1 ----
    {
        const int tok = (w & 1) * 64 + lane;           // 0..127
        const int bi  = BIL[tok];
        const int cq  = w >> 1;                        // 0..1 (32 channels each)
        const float4* eq = reinterpret_cast<const float4*>(E + bi * CCH + cq * 32);
        float* oq = out + b * CHW + (cq * 32) * HWSZ + hw0 + tok;
#pragma unroll
        for (int i = 0; i < 8; ++i) {
            float4 q = eq[i];                          // L2-hit gather
            oq[(4 * i + 0) * HWSZ] = q.x;              // coalesced across lanes
            oq[(4 * i + 1) * HWSZ] = q.y;
            oq[(4 * i + 2) * HWSZ] = q.z;
            oq[(4 * i + 3) * HWSZ] = q.w;
        }
        if (cq == 0) {                                 // waves 0,1: idx + loss
            out[NXQ + 2 + n0 + tok] = (float)bi;
            float lsum = BVL[tok] + XSL[tok];          // ||x-q||^2
#pragma unroll
            for (int off = 32; off > 0; off >>= 1)
                lsum += __shfl_xor(lsum, off, 64);
            if (lane == 0) atomicAdd(loss_acc, (double)lsum);
        }
    }
}

// ---------------------------------------------------------------------------
// Kernel 3: finalize both loss scalars (forward values identical).
// ---------------------------------------------------------------------------
__global__ void vq_final(const double* __restrict__ loss_acc,
                         float* __restrict__ out) {
    if (threadIdx.x == 0) {
        float m = (float)(*loss_acc / NMEAN);
        out[NXQ]     = m;
        out[NXQ + 1] = m;
    }
}

// ---------------------------------------------------------------------------
extern "C" void kernel_launch(void* const* d_in, const int* in_sizes, int n_in,
                              void* d_out, int out_size, void* d_ws, size_t ws_size,
                              hipStream_t stream) {
    const float* x = (const float*)d_in[0];          // [16,64,64,64] f32
    const float* E = (const float*)d_in[1];          // [1024,64] f32
    float* out = (float*)d_out;                      // [x_q | cb | cm | idx]
    double* loss_acc = (double*)d_ws;                // 8 B
    float*  e2 = (float*)((char*)d_ws + 64);         // 4 KB
    s16x8*  Bh = (s16x8*)((char*)d_ws + 8192);
    s16x8*  Bm = (s16x8*)((char*)d_ws + 8192 + PLANE_BYTES);
    s16x8*  Bl = (s16x8*)((char*)d_ws + 8192 + 2 * PLANE_BYTES);

    vq_prep <<<128, 64,  0, stream>>>(E, e2, Bh, Bm, Bl, loss_acc);
    vq_main <<<512, 256, 0, stream>>>(x, E, Bh, Bm, Bl, e2, out, loss_acc);
    vq_final<<<1,   64,  0, stream>>>(loss_acc, out);
}

// Round 11
// 126.338 us; speedup vs baseline: 2.3923x; 1.0157x over previous
//
#include <hip/hip_runtime.h>

typedef _Float16 f16x8 __attribute__((ext_vector_type(8)));  // 8 f16 (4 VGPR) MFMA frag
typedef float f32x4 __attribute__((ext_vector_type(4)));     // MFMA C/D frag

#define CCH 64
#define KCB 1024
#define HWSZ 4096
#define CHW 262144            // C*H*W
#define NXQ 4194304           // B*C*H*W
#define NMEAN 4194304.0       // N*C
#define PLANE_BYTES 131072    // 1024 codes * 64 ch * 2B
#define INV2048 0.00048828125f

// ---------------------------------------------------------------------------
// Kernel 1 (8192 thr): pack -2*E into TWO f16 planes (h, l'=2^11*residual)
// in MFMA-B frag order; e2[k]=||E[k]||^2; zero loss. Plane entry
// gid=(ntile*2+ks)*64+l holds code col=(l&15), channels c=ks*32+(l>>4)*8+j
// (same (g,j)->c map as A frags: in-fragment permutation cancels — the map
// itself is the r6/r9 HW-validated one, dtype-independent per m121/m123).
// f16 split-2: h,l' products are EXACT in f32 acc (11+11<=24 bits); scaled
// residual stays normal-range; dropped l*l ~ 2^-22 — tighter than the
// validated bf16 6-pass.
// ---------------------------------------------------------------------------
__global__ void vq_prep(const float* __restrict__ E, float* __restrict__ e2,
                        f16x8* __restrict__ Bh, f16x8* __restrict__ Bl,
                        double* __restrict__ loss_acc) {
    int gid = blockIdx.x * blockDim.x + threadIdx.x;   // 0..8191
    if (gid == 0) *loss_acc = 0.0;
    {
        int nt = gid >> 7, rem = gid & 127;
        int ks = rem >> 6, l = rem & 63;
        int code = nt * 16 + (l & 15);
        int cb   = ks * 32 + ((l >> 4) << 3);
        const float* ep = E + code * CCH + cb;
        f16x8 vh, vl;
#pragma unroll
        for (int j = 0; j < 8; ++j) {
            float v = -2.f * ep[j];                    // exact scaling
            _Float16 h = (_Float16)v;                  // RNE
            float r = v - (float)h;                    // exact residual
            vh[j] = h;
            vl[j] = (_Float16)(r * 2048.0f);           // scaled -> normal f16
        }
        Bh[gid] = vh; Bl[gid] = vl;
    }
    if (gid < KCB) {
        const float4* e4 = reinterpret_cast<const float4*>(E + gid * CCH);
        float s = 0.f;
#pragma unroll
        for (int i = 0; i < 16; ++i) {
            float4 v = e4[i];
            s = fmaf(v.x, v.x, s); s = fmaf(v.y, v.y, s);
            s = fmaf(v.z, v.z, s); s = fmaf(v.w, v.w, s);
        }
        e2[gid] = s;
    }
}

// ---------------------------------------------------------------------------
// Kernel 2: MFMA VQ. 1024 blocks x 64 thr = ONE WAVE per block, 64 tokens.
//   NO LDS / NO BARRIERS in the main loop (r9 post-mortem: lockstep
//   barriers serialized LDS|MFMA|VALU pipes -> 30% MfmaUtil). MT=4: A-frags
//   for 4 M-tiles in regs (16 f16x8); all 1024 codes swept in 32 chunks;
//   B-frags read DIRECT FROM L2 (262 MB total @34.5TB/s = 7.6us < MFMA
//   floor 13.2us) with one-chunk register double-buffer prefetch (~930 cyc
//   of MFMA ahead of use). 3 MFMA passes per (mt,nt,ks): acc0=e2+h*h,
//   acc1=h*l'+l'*h; s=acc0+acc1/2048. Per-SIMD budget: 48 MFMA x 19.4cyc
//   = 930 cyc/chunk matrix pipe; argmin VALU (~256cyc) + buf-rot movs
//   (~128cyc) issue under the MFMA shadow. Wave-local argmin over full K
//   (ch,nt asc, strict <, lower-k ties) -> first-occurrence semantics,
//   no cross-wave combine. ~200 live VGPR under (64,2) cap 256: no spill.
// ---------------------------------------------------------------------------
__global__ __launch_bounds__(64, 2) void vq_main(
    const float* __restrict__ x, const float* __restrict__ E,
    const f16x8* __restrict__ Bh, const f16x8* __restrict__ Bl,
    const float* __restrict__ e2, float* __restrict__ out,
    double* __restrict__ loss_acc)
{
    __shared__ float XSL[64];
    __shared__ float BVL[64];
    __shared__ int   BIL[64];

    const int lane = threadIdx.x;          // single wave
    const int g    = lane >> 4;
    const int c15  = lane & 15;
    const int n0   = blockIdx.x * 64;
    const int b    = n0 >> 12;             // 64 | 4096: constant per block
    const int hw0  = n0 & 4095;

    // ---- A-frags [mt][ks] from global; token = n0 + mt*16 + c15 ----
    f16x8 ah[4][2], al[4][2];
#pragma unroll
    for (int mt = 0; mt < 4; ++mt) {
        const float* xp = x + b * CHW + hw0 + mt * 16 + c15;
        float xs = 0.f;
#pragma unroll
        for (int ks = 0; ks < 2; ++ks)
#pragma unroll
            for (int j = 0; j < 8; ++j) {
                float v = xp[(ks * 32 + g * 8 + j) * HWSZ];
                xs = fmaf(v, v, xs);
                _Float16 h = (_Float16)v;
                float r = v - (float)h;
                ah[mt][ks][j] = h;
                al[mt][ks][j] = (_Float16)(r * 2048.0f);
            }
        xs += __shfl_xor(xs, 16, 64);      // fold 4 k-groups -> full ||x||^2
        xs += __shfl_xor(xs, 32, 64);
        if (lane < 16) XSL[mt * 16 + lane] = xs;
    }

    float best[4][4]; int bidx[4][4];
#pragma unroll
    for (int mt = 0; mt < 4; ++mt)
#pragma unroll
        for (int r = 0; r < 4; ++r) { best[mt][r] = 3.4e38f; bidx[mt][r] = 0; }

    // ---- prefetch chunk 0 into cur regs ----
    f16x8 cbh[2][2], cbl[2][2];            // [nt][ks]
#pragma unroll
    for (int nt = 0; nt < 2; ++nt)
#pragma unroll
        for (int ks = 0; ks < 2; ++ks) {
            int idx = (nt * 2 + ks) * 64 + lane;
            cbh[nt][ks] = Bh[idx];
            cbl[nt][ks] = Bl[idx];
        }

#pragma unroll 1
    for (int ch = 0; ch < 32; ++ch) {
        f16x8 nbh[2][2], nbl[2][2];
        if (ch < 31) {                     // issue next chunk's L2 loads NOW
#pragma unroll
            for (int nt = 0; nt < 2; ++nt)
#pragma unroll
                for (int ks = 0; ks < 2; ++ks) {
                    int idx = (((ch + 1) * 2 + nt) * 2 + ks) * 64 + lane;
                    nbh[nt][ks] = Bh[idx];
                    nbl[nt][ks] = Bl[idx];
                }
        }

#pragma unroll
        for (int nt = 0; nt < 2; ++nt) {
            const float s0 = e2[ch * 32 + nt * 16 + c15];   // seed ||e||^2
            const int k = ch * 32 + nt * 16 + c15;          // asc in (ch,nt)
#pragma unroll
            for (int mt = 0; mt < 4; ++mt) {
                f32x4 a0 = (f32x4){s0, s0, s0, s0};
                f32x4 a1 = (f32x4){0.f, 0.f, 0.f, 0.f};
#pragma unroll
                for (int ks = 0; ks < 2; ++ks) {
                    a0 = __builtin_amdgcn_mfma_f32_16x16x32_f16(ah[mt][ks], cbh[nt][ks], a0, 0, 0, 0);
                    a1 = __builtin_amdgcn_mfma_f32_16x16x32_f16(ah[mt][ks], cbl[nt][ks], a1, 0, 0, 0);
                    a1 = __builtin_amdgcn_mfma_f32_16x16x32_f16(al[mt][ks], cbh[nt][ks], a1, 0, 0, 0);
                }
#pragma unroll
                for (int r = 0; r < 4; ++r) {
                    float s = fmaf(a1[r], INV2048, a0[r]);  // h*h + (mixed)/2048
                    if (s < best[mt][r]) { best[mt][r] = s; bidx[mt][r] = k; }
                }
            }
        }

        if (ch < 31) {
#pragma unroll
            for (int nt = 0; nt < 2; ++nt)
#pragma unroll
                for (int ks = 0; ks < 2; ++ks) {
                    cbh[nt][ks] = nbh[nt][ks];
                    cbl[nt][ks] = nbl[nt][ks];
                }
        }
    }

    // ---- wave-local argmin reduce over 16 code-cols (tie -> lower k) ----
#pragma unroll
    for (int mt = 0; mt < 4; ++mt)
#pragma unroll
        for (int r = 0; r < 4; ++r) {
            float v = best[mt][r]; int k = bidx[mt][r];
#pragma unroll
            for (int off = 1; off < 16; off <<= 1) {
                float ov = __shfl_xor(v, off, 64);
                int   ok = __shfl_xor(k, off, 64);
                if (ov < v || (ov == v && ok < k)) { v = ov; k = ok; }
            }
            if (c15 == 0) {                // token row = g*4 + r (m89 map)
                BVL[mt * 16 + g * 4 + r] = v;
                BIL[mt * 16 + g * 4 + r] = k;
            }
        }
    __syncthreads();                       // 1 wave: compiles to cheap wait

    // ---- epilogue: lane owns token n0+lane ----
    {
        const int bi = BIL[lane];
        out[NXQ + 2 + n0 + lane] = (float)bi;

        float lsum = BVL[lane] + XSL[lane];        // ||x-q||^2
#pragma unroll
        for (int off = 32; off > 0; off >>= 1)
            lsum += __shfl_xor(lsum, off, 64);
        if (lane == 0) atomicAdd(loss_acc, (double)lsum);

        // x_q = E[bi] (exact f32), coalesced per-channel scatter
        const float4* eq = reinterpret_cast<const float4*>(E + bi * CCH);
        float* oq = out + b * CHW + hw0 + lane;
#pragma unroll 1
        for (int gq = 0; gq < 4; ++gq) {
            float4 q0 = eq[4 * gq + 0];
            float4 q1 = eq[4 * gq + 1];
            float4 q2 = eq[4 * gq + 2];
            float4 q3 = eq[4 * gq + 3];
            float* o = oq + (16 * gq) * HWSZ;
            o[0 * HWSZ]  = q0.x; o[1 * HWSZ]  = q0.y; o[2 * HWSZ]  = q0.z; o[3 * HWSZ]  = q0.w;
            o[4 * HWSZ]  = q1.x; o[5 * HWSZ]  = q1.y; o[6 * HWSZ]  = q1.z; o[7 * HWSZ]  = q1.w;
            o[8 * HWSZ]  = q2.x; o[9 * HWSZ]  = q2.y; o[10 * HWSZ] = q2.z; o[11 * HWSZ] = q2.w;
            o[12 * HWSZ] = q3.x; o[13 * HWSZ] = q3.y; o[14 * HWSZ] = q3.z; o[15 * HWSZ] = q3.w;
        }
    }
}

// ---------------------------------------------------------------------------
// Kernel 3: finalize both loss scalars (forward values identical).
// ---------------------------------------------------------------------------
__global__ void vq_final(const double* __restrict__ loss_acc,
                         float* __restrict__ out) {
    if (threadIdx.x == 0) {
        float m = (float)(*loss_acc / NMEAN);
        out[NXQ]     = m;
        out[NXQ + 1] = m;
    }
}

// ---------------------------------------------------------------------------
extern "C" void kernel_launch(void* const* d_in, const int* in_sizes, int n_in,
                              void* d_out, int out_size, void* d_ws, size_t ws_size,
                              hipStream_t stream) {
    const float* x = (const float*)d_in[0];          // [16,64,64,64] f32
    const float* E = (const float*)d_in[1];          // [1024,64] f32
    float* out = (float*)d_out;                      // [x_q | cb | cm | idx]
    double* loss_acc = (double*)d_ws;                // 8 B
    float*  e2 = (float*)((char*)d_ws + 64);         // 4 KB
    f16x8*  Bh = (f16x8*)((char*)d_ws + 8192);       // 128 KB
    f16x8*  Bl = (f16x8*)((char*)d_ws + 8192 + PLANE_BYTES);

    vq_prep <<<128,  64, 0, stream>>>(E, e2, Bh, Bl, loss_acc);
    vq_main <<<1024, 64, 0, stream>>>(x, E, Bh, Bl, e2, out, loss_acc);
    vq_final<<<1,    64, 0, stream>>>(loss_acc, out);
}